// Round 5
// baseline (106.204 us; speedup 1.0000x reference)
//
#include <hip/hip_runtime.h>
#include <hip/hip_bf16.h>
#include <math.h>

// Collapsed math (softmax over the size-1 summary axis == 1 identically, so
// q/Wq/Wk/bias-MLP/mask-bias are dead code):
//   summary[bn,:] = sum_t m*x / max(sum_t m, 1e-6)
//   v[bn,:]       = summary @ Wv + bv
//   rf[bn,t]      = [dx,dy,dz,||d||,||d||^2] vs masked-mean position
//   rel_val       = gelu_exact(rf @ Vw1 + Vb1) @ Vw2 + Vb2   (bf16 MFMA)
//   out[bn,t,:]   = x[bn,t,:] + v[bn,:] + rel_val[bn,t,:]
//
// Round-5: occupancy attack. k_sum was 2 blocks/CU streaming 134MB; k_main's
// unified VGPR+AGPR (~124) capped it at 4 waves/SIMD with only 2 block-rounds.
//  k_part: 2048 streaming blocks (<=64 VGPR, 8 waves/SIMD) -> tile partials.
//  k_v   : 512 tiny blocks combine partials -> v, pos-mean.
//  k_main: 32-token tiles (grid 4096), acc 2x4 (32 regs) -> 4 block-rounds.

#define BN_TOT 512
#define T_DIM 256
#define D_DIM 256
#define HID 128

typedef __attribute__((ext_vector_type(8))) short short8v;
typedef __attribute__((ext_vector_type(4))) float f32x4;

static __device__ __forceinline__ ushort f2bf(float f) {
    __hip_bfloat16 h = __float2bfloat16(f);
    return *reinterpret_cast<ushort*>(&h);
}

// ---- prep: Vw2 [128][256] f32 -> Vw2t [256][128] bf16 (transposed) ----
__global__ __launch_bounds__(256) void k_prep(const float* __restrict__ Vw2,
                                              ushort* __restrict__ Vw2t) {
    const int idx = (blockIdx.x * 256 + threadIdx.x) * 4;   // grid 32 -> 32768 elems
    const int d = idx >> 7, k = idx & 127;
    ushort4 r;
    r.x = f2bf(Vw2[(size_t)(k + 0) * D_DIM + d]);
    r.y = f2bf(Vw2[(size_t)(k + 1) * D_DIM + d]);
    r.z = f2bf(Vw2[(size_t)(k + 2) * D_DIM + d]);
    r.w = f2bf(Vw2[(size_t)(k + 3) * D_DIM + d]);
    *reinterpret_cast<ushort4*>(Vw2t + d * HID + k) = r;
}

// ---- K1a: per-(bn, 64-token tile) partials: masked column sums + cnt/pos ----
__global__ __launch_bounds__(256, 8) void k_part(
    const float* __restrict__ x,      // [BN,T,D]
    const int* __restrict__ masks,    // [BN,T]
    const float* __restrict__ pos,    // [BN,T,3]
    float* __restrict__ part_x,       // [BN,4,256]
    float* __restrict__ part_cp)      // [BN,4,4] (cnt,px,py,pz)
{
    __shared__ float s_part[4 * 256];

    const int bid = blockIdx.x;
    const int tid = threadIdx.x;
    const int bn = bid >> 2, tg = bid & 3;
    const int t0 = tg * 64;

    const float* xb = x + ((size_t)bn * T_DIM + t0) * D_DIM;
    const int*   mb = masks + bn * T_DIM + t0;

    // masked column sums over this 64-token tile
    {
        const int dq = tid & 63, tq = tid >> 6;   // wave == one tq
        float4 a = make_float4(0.f, 0.f, 0.f, 0.f);
        #pragma unroll
        for (int i = 0; i < 16; ++i) {
            const int t = tq * 16 + i;            // wave-uniform
            float m = (float)mb[t];
            float4 xv = *reinterpret_cast<const float4*>(xb + (size_t)t * D_DIM + dq * 4);
            a.x += m * xv.x; a.y += m * xv.y; a.z += m * xv.z; a.w += m * xv.w;
        }
        *reinterpret_cast<float4*>(s_part + tq * 256 + dq * 4) = a;
    }

    // mask count + masked pos sums for this tile (wave 0, shfl reduce)
    if (tid < 64) {
        float m = (float)mb[tid];
        const float* pp = pos + ((size_t)bn * T_DIM + t0 + tid) * 3;
        float c = m, px = m * pp[0], py = m * pp[1], pz = m * pp[2];
        #pragma unroll
        for (int off = 32; off > 0; off >>= 1) {
            c  += __shfl_down(c,  off, 64);
            px += __shfl_down(px, off, 64);
            py += __shfl_down(py, off, 64);
            pz += __shfl_down(pz, off, 64);
        }
        if (tid == 0)
            *reinterpret_cast<float4*>(part_cp + (bn * 4 + tg) * 4) =
                make_float4(c, px, py, pz);
    }
    __syncthreads();

    float s = s_part[tid] + s_part[256 + tid] + s_part[512 + tid] + s_part[768 + tid];
    part_x[((size_t)bn * 4 + tg) * 256 + tid] = s;
}

// ---- K1b: combine partials -> summary; v = summary @ Wv + bv + Vb2 ----
__global__ __launch_bounds__(256, 8) void k_v(
    const float* __restrict__ part_x,  // [BN,4,256]
    const float* __restrict__ part_cp, // [BN,4,4]
    const float* __restrict__ Wv,      // [D,D]
    const float* __restrict__ bv,
    const float* __restrict__ Vb2,
    float* __restrict__ v_ws,          // [BN,D]
    float* __restrict__ ps_ws)         // [BN,4]
{
    __shared__ float s_sum[256];
    __shared__ float s_part[4 * 256];
    __shared__ float s_cp[16];

    const int bn = blockIdx.x, tid = threadIdx.x;

    if (tid < 16) s_cp[tid] = part_cp[bn * 16 + tid];
    const float* pb = part_x + (size_t)bn * 1024;
    float s = pb[tid] + pb[256 + tid] + pb[512 + tid] + pb[768 + tid];
    __syncthreads();

    const float cnt = s_cp[0] + s_cp[4] + s_cp[8] + s_cp[12];
    const float inv = 1.0f / fmaxf(cnt, 1e-6f);
    s_sum[tid] = s * inv;
    if (tid < 3) {
        float p = s_cp[tid + 1] + s_cp[tid + 5] + s_cp[tid + 9] + s_cp[tid + 13];
        ps_ws[bn * 4 + tid] = p * inv;
    }
    __syncthreads();

    // v = summary @ Wv : 64 float4-chunks x 4 k-groups of 64
    {
        const int dq = tid & 63, kq = tid >> 6;
        float4 a = make_float4(0.f, 0.f, 0.f, 0.f);
        #pragma unroll 8
        for (int i = 0; i < 64; ++i) {
            const int k = kq * 64 + i;
            float sc = s_sum[k];
            float4 w = *reinterpret_cast<const float4*>(Wv + (size_t)k * D_DIM + dq * 4);
            a.x += sc * w.x; a.y += sc * w.y; a.z += sc * w.z; a.w += sc * w.w;
        }
        *reinterpret_cast<float4*>(s_part + kq * 256 + dq * 4) = a;
    }
    __syncthreads();
    v_ws[bn * D_DIM + tid] = s_part[tid] + s_part[256 + tid] + s_part[512 + tid] +
                             s_part[768 + tid] + bv[tid] + Vb2[tid];
}

// ---- fallback K1 (round-4, known good): used when ws_size is small ----
__global__ __launch_bounds__(512, 8) void k_sum(
    const float* __restrict__ x, const int* __restrict__ masks,
    const float* __restrict__ pos, const float* __restrict__ Wv,
    const float* __restrict__ bv, const float* __restrict__ Vb2,
    float* __restrict__ v_ws, float* __restrict__ ps_ws)
{
    __shared__ float s_m[256];
    __shared__ float s_red[4 * 256];
    __shared__ float s_part[8 * 256];
    __shared__ float s_sum[256];

    const int bn = blockIdx.x, tid = threadIdx.x;
    const float* xb = x + (size_t)bn * T_DIM * D_DIM;

    if (tid < 256) {
        float m = (float)masks[bn * T_DIM + tid];
        s_m[tid] = m;
        const float* pp = pos + ((size_t)bn * T_DIM + tid) * 3;
        s_red[0 * 256 + tid] = m;
        s_red[1 * 256 + tid] = m * pp[0];
        s_red[2 * 256 + tid] = m * pp[1];
        s_red[3 * 256 + tid] = m * pp[2];
    }
    __syncthreads();
    {
        const int dq = tid & 63, tq = tid >> 6;
        float4 a = make_float4(0.f, 0.f, 0.f, 0.f);
        const float* px = xb + (size_t)tq * 32 * D_DIM + dq * 4;
        #pragma unroll 8
        for (int i = 0; i < 32; ++i) {
            float m = s_m[tq * 32 + i];
            float4 xv = *reinterpret_cast<const float4*>(px + i * D_DIM);
            a.x += m * xv.x; a.y += m * xv.y; a.z += m * xv.z; a.w += m * xv.w;
        }
        *reinterpret_cast<float4*>(s_part + tq * 256 + dq * 4) = a;
    }
    __syncthreads();
    for (int off = 128; off > 0; off >>= 1) {
        if (tid < off) {
            s_red[0 * 256 + tid] += s_red[0 * 256 + tid + off];
            s_red[1 * 256 + tid] += s_red[1 * 256 + tid + off];
            s_red[2 * 256 + tid] += s_red[2 * 256 + tid + off];
            s_red[3 * 256 + tid] += s_red[3 * 256 + tid + off];
        }
        __syncthreads();
    }
    const float inv = 1.0f / fmaxf(s_red[0], 1e-6f);
    if (tid < 3) ps_ws[bn * 4 + tid] = s_red[(tid + 1) * 256] * inv;
    if (tid < 256) {
        float s = 0.f;
        #pragma unroll
        for (int q = 0; q < 8; ++q) s += s_part[q * 256 + tid];
        s_sum[tid] = s * inv;
    }
    __syncthreads();
    {
        const int dq = tid & 63, kq = tid >> 6;
        float4 a = make_float4(0.f, 0.f, 0.f, 0.f);
        #pragma unroll 8
        for (int i = 0; i < 32; ++i) {
            const int k = kq * 32 + i;
            float sc = s_sum[k];
            float4 w = *reinterpret_cast<const float4*>(Wv + (size_t)k * D_DIM + dq * 4);
            a.x += sc * w.x; a.y += sc * w.y; a.z += sc * w.z; a.w += sc * w.w;
        }
        *reinterpret_cast<float4*>(s_part + kq * 256 + dq * 4) = a;
    }
    __syncthreads();
    if (tid < 256) {
        float r = bv[tid] + Vb2[tid];
        #pragma unroll
        for (int q = 0; q < 8; ++q) r += s_part[q * 256 + tid];
        v_ws[bn * D_DIM + tid] = r;
    }
}

// ---- K2: hidden MLP + MFMA GEMM + float4 residual epilogue ----
// grid (8, 512): 32-token tile per block; 256 threads (4 waves), acc 2x4.
__global__ __launch_bounds__(256, 4) void k_main(
    const float* __restrict__ x,
    const float* __restrict__ pos,
    const float* __restrict__ Vw1,    // [5,128]
    const float* __restrict__ Vb1,    // [128]
    const ushort* __restrict__ Vw2t,  // [256][128] bf16
    const float* __restrict__ v_ws,   // [BN,256] (= v + bv + Vb2)
    const float* __restrict__ ps_ws,  // [BN,4]
    float* __restrict__ out)
{
    __shared__ float s_rf[32 * 6];                  // 768 B
    __shared__ float s_w1[5 * 128];                 // 2.5 KB
    __shared__ float s_b1[128];                     // 0.5 KB
    __shared__ float s_vb[256];                     // 1 KB
    __shared__ unsigned char s_hid[32 * HID * 2];   // 8 KB bf16, XOR-swizzled

    const int tg  = blockIdx.x;           // token group of 32
    const int bn  = blockIdx.y;
    const int tid = threadIdx.x;
    const int t0  = tg * 32;

    s_vb[tid] = v_ws[bn * D_DIM + tid];
    for (int i = tid; i < 640; i += 256) s_w1[i] = Vw1[i];
    if (tid < 128) s_b1[tid] = Vb1[tid];

    const float psx = ps_ws[bn * 4 + 0];
    const float psy = ps_ws[bn * 4 + 1];
    const float psz = ps_ws[bn * 4 + 2];
    if (tid < 32) {
        const float* pp = pos + ((size_t)bn * T_DIM + t0 + tid) * 3;
        float dx = pp[0] - psx, dy = pp[1] - psy, dz = pp[2] - psz;
        float d2 = dx * dx + dy * dy + dz * dz;
        s_rf[tid * 6 + 0] = dx; s_rf[tid * 6 + 1] = dy; s_rf[tid * 6 + 2] = dz;
        s_rf[tid * 6 + 3] = sqrtf(d2); s_rf[tid * 6 + 4] = d2;
    }
    __syncthreads();

    // hidden = gelu_exact(rf @ Vw1 + Vb1) -> bf16 LDS (swizzled, [tok][128ch])
    {
        const int cg = tid & 15;          // 8 channels: c0..c0+7
        const int c0 = cg * 8;
        float wv[5][8], bb[8];
        #pragma unroll
        for (int e = 0; e < 5; ++e)
            #pragma unroll
            for (int j = 0; j < 8; ++j) wv[e][j] = s_w1[e * HID + c0 + j];
        #pragma unroll
        for (int j = 0; j < 8; ++j) bb[j] = s_b1[c0 + j];

        #pragma unroll
        for (int s = 0; s < 2; ++s) {
            const int tok = (tid >> 4) + s * 16;    // local 0..31
            const float* rf = s_rf + tok * 6;
            const float dx = rf[0], dy = rf[1], dz = rf[2], dd = rf[3], d2 = rf[4];
            uint pk[4];
            #pragma unroll
            for (int jj = 0; jj < 4; ++jj) {
                float g[2];
                #pragma unroll
                for (int h = 0; h < 2; ++h) {
                    const int j = jj * 2 + h;
                    float z = bb[j] + dx * wv[0][j] + dy * wv[1][j] + dz * wv[2][j]
                                    + dd * wv[3][j] + d2 * wv[4][j];
                    g[h] = 0.5f * z * (1.0f + erff(z * 0.70710678118654752f));
                }
                pk[jj] = (uint)f2bf(g[0]) | ((uint)f2bf(g[1]) << 16);
            }
            int byte = tok * 256 + cg * 16;
            byte ^= (tok & 15) << 4;
            *reinterpret_cast<uint4*>(s_hid + byte) = make_uint4(pk[0], pk[1], pk[2], pk[3]);
        }
    }
    __syncthreads();

    // GEMM (operand-swapped): D = Wfrag @ hidfrag = rel_val^T.
    // Lane l of wave wc: tok = m*16 + (l&15), d = wc*64 + n*16 + 4*(l>>4) + r
    const int l  = tid & 63;
    const int wc = tid >> 6;              // d quarter (64 cols)

    f32x4 acc[2][4];
    #pragma unroll
    for (int m = 0; m < 2; ++m)
        #pragma unroll
        for (int n = 0; n < 4; ++n) acc[m][n] = (f32x4){0.f, 0.f, 0.f, 0.f};

    const ushort* bbase = Vw2t + ((size_t)(wc * 64 + (l & 15))) * HID + ((l >> 4) * 8);
    const int koff16 = (l >> 4) * 16;

    #pragma unroll
    for (int ks = 0; ks < 4; ++ks) {
        short8v wfr[4];
        #pragma unroll
        for (int n = 0; n < 4; ++n)
            wfr[n] = *reinterpret_cast<const short8v*>(bbase + n * 16 * HID + ks * 32);
        short8v hfr[2];
        #pragma unroll
        for (int m = 0; m < 2; ++m) {
            const int tok = m * 16 + (l & 15);
            int byte = tok * 256 + ks * 64 + koff16;
            byte ^= (tok & 15) << 4;
            hfr[m] = *reinterpret_cast<const short8v*>(s_hid + byte);
        }
        #pragma unroll
        for (int m = 0; m < 2; ++m)
            #pragma unroll
            for (int n = 0; n < 4; ++n)
                acc[m][n] = __builtin_amdgcn_mfma_f32_16x16x32_bf16(
                    wfr[n], hfr[m], acc[m][n], 0, 0, 0);
    }

    // epilogue: out = x + (v+bv+Vb2) + rel_val  (float4 throughout)
    #pragma unroll
    for (int m = 0; m < 2; ++m) {
        const int tok = m * 16 + (l & 15);
        const float* xr   = x   + ((size_t)bn * T_DIM + t0 + tok) * D_DIM;
        float*       orow = out + ((size_t)bn * T_DIM + t0 + tok) * D_DIM;
        #pragma unroll
        for (int n = 0; n < 4; ++n) {
            const int d0 = wc * 64 + n * 16 + ((l >> 4) << 2);
            float4 xv  = *reinterpret_cast<const float4*>(xr + d0);
            float4 vb4 = *reinterpret_cast<const float4*>(s_vb + d0);
            float4 o;
            o.x = xv.x + vb4.x + acc[m][n][0];
            o.y = xv.y + vb4.y + acc[m][n][1];
            o.z = xv.z + vb4.z + acc[m][n][2];
            o.w = xv.w + vb4.w + acc[m][n][3];
            *reinterpret_cast<float4*>(orow + d0) = o;
        }
    }
}

extern "C" void kernel_launch(void* const* d_in, const int* in_sizes, int n_in,
                              void* d_out, int out_size, void* d_ws, size_t ws_size,
                              hipStream_t stream) {
    const float* x     = (const float*)d_in[0];
    // d_in[1] = sum_token (unused by reference)
    const int*   masks = (const int*)d_in[2];
    const float* pos   = (const float*)d_in[3];
    // d_in[4..7] = Wq,bq,Wk,bk (dead: softmax over size-1 axis == 1)
    const float* Wv    = (const float*)d_in[8];
    const float* bv    = (const float*)d_in[9];
    // d_in[10..13] = bias-MLP (dead)
    const float* Vw1   = (const float*)d_in[14];
    const float* Vb1   = (const float*)d_in[15];
    const float* Vw2   = (const float*)d_in[16];
    const float* Vb2   = (const float*)d_in[17];
    float* out = (float*)d_out;

    // ws layout
    ushort* Vw2t  = (ushort*)d_ws;                          // 64 KB
    float*  v_ws  = (float*)(Vw2t + D_DIM * HID);           // 512 KB
    float*  ps_ws = v_ws + BN_TOT * D_DIM;                  // 8 KB
    float*  part_x  = ps_ws + BN_TOT * 4;                   // 2 MB
    float*  part_cp = part_x + (size_t)BN_TOT * 4 * 256;    // 32 KB
    const size_t need_main = (size_t)(part_cp + BN_TOT * 16 - (float*)d_ws) * 4;

    k_prep<<<32, 256, 0, stream>>>(Vw2, Vw2t);
    if (ws_size >= need_main) {
        k_part<<<BN_TOT * 4, 256, 0, stream>>>(x, masks, pos, part_x, part_cp);
        k_v<<<BN_TOT, 256, 0, stream>>>(part_x, part_cp, Wv, bv, Vb2, v_ws, ps_ws);
    } else {
        k_sum<<<BN_TOT, 512, 0, stream>>>(x, masks, pos, Wv, bv, Vb2, v_ws, ps_ws);
    }
    k_main<<<dim3(8, BN_TOT), 256, 0, stream>>>(x, pos, Vw1, Vb1, Vw2t,
                                                v_ws, ps_ws, out);
}